// Round 1
// baseline (115.042 us; speedup 1.0000x reference)
//
#include <hip/hip_runtime.h>
#include <stdint.h>

#define D_ 384
#define NPTS 4096

// ---------------- Threefry-2x32 (JAX-exact, 20 rounds) ----------------
__device__ __forceinline__ void tf_round(uint32_t& x0, uint32_t& x1, int r) {
  x0 += x1;
  x1 = (x1 << r) | (x1 >> (32 - r));
  x1 ^= x0;
}

__device__ void tf2x32(uint32_t k0, uint32_t k1, uint32_t x0, uint32_t x1,
                       uint32_t& y0, uint32_t& y1) {
  uint32_t ks2 = k0 ^ k1 ^ 0x1BD11BDAu;
  x0 += k0; x1 += k1;
  tf_round(x0, x1, 13); tf_round(x0, x1, 15); tf_round(x0, x1, 26); tf_round(x0, x1, 6);
  x0 += k1; x1 += ks2 + 1u;
  tf_round(x0, x1, 17); tf_round(x0, x1, 29); tf_round(x0, x1, 16); tf_round(x0, x1, 24);
  x0 += ks2; x1 += k0 + 2u;
  tf_round(x0, x1, 13); tf_round(x0, x1, 15); tf_round(x0, x1, 26); tf_round(x0, x1, 6);
  x0 += k0; x1 += k1 + 3u;
  tf_round(x0, x1, 17); tf_round(x0, x1, 29); tf_round(x0, x1, 16); tf_round(x0, x1, 24);
  x0 += k1; x1 += ks2 + 4u;
  tf_round(x0, x1, 13); tf_round(x0, x1, 15); tf_round(x0, x1, 26); tf_round(x0, x1, 6);
  x0 += ks2; x1 += k0 + 5u;
  y0 = x0; y1 = x1;
}

// ---------------- Pooling: hierarchical block means ----------------
// Grid: 32 batches * 16 s4-cells = 512 blocks, 384 threads (one per dim d).
// ws layout (floats): w4 [32*16*384] @0, w8 [32*64*384] @196608, w16 [32*256*384] @983040
__global__ __launch_bounds__(384) void pool_kernel(const float* __restrict__ feats,
                                                   float* __restrict__ ws) {
  int blk = blockIdx.x;
  int b = blk >> 4;
  int cell = blk & 15;
  int P = cell >> 2, Q = cell & 3;     // s=4 cell coords
  int d = threadIdx.x;                 // 0..383
  const float* fb = feats + (size_t)b * NPTS * D_;
  float* w4  = ws;
  float* w8  = ws + 196608;
  float* w16 = ws + 983040;

  float s4 = 0.f;
  for (int sp = 0; sp < 2; ++sp)
    for (int sq = 0; sq < 2; ++sq) {
      float s8 = 0.f;
      for (int p2 = 0; p2 < 2; ++p2)
        for (int q2 = 0; q2 < 2; ++q2) {
          int ch = P * 4 + sp * 2 + p2;   // s=16 cell row 0..15
          int cw = Q * 4 + sq * 2 + q2;   // s=16 cell col 0..15
          float s16 = 0.f;
          for (int dh = 0; dh < 4; ++dh)
            for (int dw = 0; dw < 4; ++dw) {
              int h = ch * 4 + dh, w = cw * 4 + dw;
              s16 += fb[((size_t)(h * 64 + w)) * D_ + d];
            }
          w16[((size_t)b * 256 + ch * 16 + cw) * D_ + d] = s16 * (1.f / 16.f);
          s8 += s16;
        }
      w8[((size_t)b * 64 + (P * 2 + sp) * 8 + (Q * 2 + sq)) * D_ + d] = s8 * (1.f / 64.f);
      s4 += s8;
    }
  w4[((size_t)b * 16 + P * 4 + Q) * D_ + d] = s4 * (1.f / 256.f);
}

// ---------------- k-means++ seeding, JAX partitionable-threefry exact ----------------
// Grid: 96 blocks (si = blk/32 in {0,1,2} -> s in {4,8,16}; b = blk%32), 256 threads.
__global__ __launch_bounds__(256) void kmeans_kernel(const float* __restrict__ ws,
                                                     float* __restrict__ out) {
  int blk = blockIdx.x;
  int si = blk / 32;
  int b  = blk % 32;
  int n  = (si == 0) ? 16 : (si == 1) ? 64 : 256;

  const float* pooled;
  if (si == 0)      pooled = ws + (size_t)b * 16  * D_;
  else if (si == 1) pooled = ws + 196608 + (size_t)b * 64  * D_;
  else              pooled = ws + 983040 + (size_t)b * 256 * D_;
  float* ob = out + ((size_t)b * 12 + si * 4) * D_;

  __shared__ float minsq[256];
  __shared__ float zsh[256];
  __shared__ float csh[D_];
  __shared__ uint32_t skey[3][2];
  __shared__ int sidx;
  __shared__ float ssum;

  int tid = threadIdx.x;

  if (tid == 0) {
    // base = key(42) = (0,42); folded = fold_in(base, si) = threefry(base, (0,si))
    uint32_t f0, f1;
    tf2x32(0u, 42u, 0u, (uint32_t)si, f0, f1);
    // bkeys = split(folded, 32)[b] = threefry(folded, (0,b))   [partitionable foldlike]
    uint32_t bk0, bk1;
    tf2x32(f0, f1, 0u, (uint32_t)b, bk0, bk1);
    // k0, k1 = split(bkey)
    uint32_t k00, k01, k10, k11;
    tf2x32(bk0, bk1, 0u, 0u, k00, k01);
    tf2x32(bk0, bk1, 0u, 1u, k10, k11);
    // randint(k0, (), 0, n): _, kk2 = split(k0); lower = random_bits(kk2, 32, ())
    // span = n (pow2), multiplier = (2^16 % n)^2 % n = 0  ->  idx0 = lower % n
    uint32_t q0, q1, l0, l1;
    tf2x32(k00, k01, 0u, 1u, q0, q1);
    tf2x32(q0, q1, 0u, 0u, l0, l1);
    uint32_t lower = l0 ^ l1;   // partitionable random_bits: y0 ^ y1
    sidx = (int)(lower & (uint32_t)(n - 1));
    // step keys = split(k1, 3)
    for (int t = 0; t < 3; ++t) {
      uint32_t a, bb;
      tf2x32(k10, k11, 0u, (uint32_t)t, a, bb);
      skey[t][0] = a; skey[t][1] = bb;
    }
  }
  __syncthreads();

  // c0: load into LDS, write to output slot 0
  for (int j = tid; j < D_; j += 256) {
    float v = pooled[(size_t)sidx * D_ + j];
    csh[j] = v;
    ob[j] = v;
  }
  __syncthreads();

  // min_sq = ||feats - c0||^2
  if (tid < n) {
    float acc = 0.f;
    const float* row = pooled + (size_t)tid * D_;
    for (int j = 0; j < D_; ++j) { float df = row[j] - csh[j]; acc += df * df; }
    minsq[tid] = acc;
  }
  __syncthreads();

  const float TINY = __uint_as_float(0x00800000u);  // FLT_MIN = finfo(f32).tiny

  for (int t = 0; t < 3; ++t) {
    // sum(min_sq) + 1e-8
    if (tid == 0) {
      float s = 0.f;
      for (int i = 0; i < n; ++i) s += minsq[i];
      ssum = s + 1e-8f;
    }
    __syncthreads();

    // z_i = gumbel_i + log(prob_i + 1e-12)
    if (tid < n) {
      float prob  = minsq[tid] / ssum;
      float logit = logf(prob + 1e-12f);
      uint32_t y0, y1;
      tf2x32(skey[t][0], skey[t][1], 0u, (uint32_t)tid, y0, y1);
      uint32_t bits = y0 ^ y1;                                  // partitionable bits
      float f = __uint_as_float((bits >> 9) | 0x3F800000u) - 1.0f;
      float u = (f > 0.f) ? f : TINY;                           // max(tiny, f*(1-tiny)+tiny)
      float g = -logf(-logf(u));
      zsh[tid] = g + logit;
    }
    __syncthreads();

    // argmax, first occurrence wins (jnp.argmax semantics)
    if (tid == 0) {
      float best = zsh[0]; int bi = 0;
      for (int i = 1; i < n; ++i) if (zsh[i] > best) { best = zsh[i]; bi = i; }
      sidx = bi;
    }
    __syncthreads();

    // gather center, write out
    for (int j = tid; j < D_; j += 256) {
      float v = pooled[(size_t)sidx * D_ + j];
      csh[j] = v;
      ob[(size_t)(t + 1) * D_ + j] = v;
    }
    __syncthreads();

    // min_sq = min(min_sq, ||feats - c||^2)
    if (tid < n) {
      float acc = 0.f;
      const float* row = pooled + (size_t)tid * D_;
      for (int j = 0; j < D_; ++j) { float df = row[j] - csh[j]; acc += df * df; }
      minsq[tid] = fminf(minsq[tid], acc);
    }
    __syncthreads();
  }
}

extern "C" void kernel_launch(void* const* d_in, const int* in_sizes, int n_in,
                              void* d_out, int out_size, void* d_ws, size_t ws_size,
                              hipStream_t stream) {
  const float* feats = (const float*)d_in[0];
  float* out = (float*)d_out;
  float* ws  = (float*)d_ws;   // needs 16,515,072 bytes (4,128,768 floats)

  pool_kernel<<<512, 384, 0, stream>>>(feats, ws);
  kmeans_kernel<<<96, 256, 0, stream>>>(ws, out);
}

// Round 2
// 87.953 us; speedup vs baseline: 1.3080x; 1.3080x over previous
//
#include <hip/hip_runtime.h>
#include <stdint.h>

#define D_ 384
#define NPTS 4096

// ---------------- Threefry-2x32 (JAX-exact, 20 rounds) ----------------
__device__ __forceinline__ void tf_round(uint32_t& x0, uint32_t& x1, int r) {
  x0 += x1;
  x1 = (x1 << r) | (x1 >> (32 - r));
  x1 ^= x0;
}

__device__ void tf2x32(uint32_t k0, uint32_t k1, uint32_t x0, uint32_t x1,
                       uint32_t& y0, uint32_t& y1) {
  uint32_t ks2 = k0 ^ k1 ^ 0x1BD11BDAu;
  x0 += k0; x1 += k1;
  tf_round(x0, x1, 13); tf_round(x0, x1, 15); tf_round(x0, x1, 26); tf_round(x0, x1, 6);
  x0 += k1; x1 += ks2 + 1u;
  tf_round(x0, x1, 17); tf_round(x0, x1, 29); tf_round(x0, x1, 16); tf_round(x0, x1, 24);
  x0 += ks2; x1 += k0 + 2u;
  tf_round(x0, x1, 13); tf_round(x0, x1, 15); tf_round(x0, x1, 26); tf_round(x0, x1, 6);
  x0 += k0; x1 += k1 + 3u;
  tf_round(x0, x1, 17); tf_round(x0, x1, 29); tf_round(x0, x1, 16); tf_round(x0, x1, 24);
  x0 += k1; x1 += ks2 + 4u;
  tf_round(x0, x1, 13); tf_round(x0, x1, 15); tf_round(x0, x1, 26); tf_round(x0, x1, 6);
  x0 += ks2; x1 += k0 + 5u;
  y0 = x0; y1 = x1;
}

// ---------------- Pooling: hierarchical block means, float4 + shfl ----------------
// Grid: 32 batches * 16 s4-cells = 512 blocks, 384 threads.
// Thread t: pslot = t&3 (w-offset within a 4-wide strip), q = t>>2 (dim quad).
// ws layout (floats): w4 [32*16*384] @0, w8 [32*64*384] @196608, w16 [32*256*384] @983040
__global__ __launch_bounds__(384) void pool_kernel(const float* __restrict__ feats,
                                                   float* __restrict__ ws) {
  int blk = blockIdx.x;
  int b = blk >> 4;
  int cell = blk & 15;
  int P = cell >> 2, Q = cell & 3;     // s=4 cell coords
  int t = threadIdx.x;
  int pslot = t & 3;                   // dw within strip
  int q = t >> 2;                      // dim quad 0..95
  const float* fb = feats + (size_t)b * NPTS * D_;
  float* w4  = ws;
  float* w8  = ws + 196608;
  float* w16 = ws + 983040;

  float s8x[2][2], s8y[2][2], s8z[2][2], s8w[2][2];
  for (int a = 0; a < 2; ++a)
    for (int c2 = 0; c2 < 2; ++c2) { s8x[a][c2]=0.f; s8y[a][c2]=0.f; s8z[a][c2]=0.f; s8w[a][c2]=0.f; }
  float s4x = 0.f, s4y = 0.f, s4z = 0.f, s4w = 0.f;

  #pragma unroll
  for (int i = 0; i < 4; ++i) {
    #pragma unroll
    for (int j = 0; j < 4; ++j) {
      float ax = 0.f, ay = 0.f, az = 0.f, aw = 0.f;
      #pragma unroll
      for (int dh = 0; dh < 4; ++dh) {
        int h = P * 16 + i * 4 + dh;
        int w = Q * 16 + j * 4 + pslot;
        const float4 v = *(const float4*)(fb + ((size_t)(h * 64 + w)) * D_ + q * 4);
        ax += v.x; ay += v.y; az += v.z; aw += v.w;
      }
      // reduce across the 4 pslot lanes (same wave; group of 4)
      ax += __shfl_xor(ax, 1); ay += __shfl_xor(ay, 1); az += __shfl_xor(az, 1); aw += __shfl_xor(aw, 1);
      ax += __shfl_xor(ax, 2); ay += __shfl_xor(ay, 2); az += __shfl_xor(az, 2); aw += __shfl_xor(aw, 2);
      // all 4 lanes now hold the s16 sum for dim quad q
      if (pslot == 0) {
        float4 o = { ax * (1.f/16.f), ay * (1.f/16.f), az * (1.f/16.f), aw * (1.f/16.f) };
        *(float4*)(w16 + ((size_t)b * 256 + (P * 4 + i) * 16 + (Q * 4 + j)) * D_ + q * 4) = o;
      }
      int i2 = i >> 1, j2 = j >> 1;
      s8x[i2][j2] += ax; s8y[i2][j2] += ay; s8z[i2][j2] += az; s8w[i2][j2] += aw;
      s4x += ax; s4y += ay; s4z += az; s4w += aw;
    }
  }
  if (pslot == 0) {
    #pragma unroll
    for (int i2 = 0; i2 < 2; ++i2)
      #pragma unroll
      for (int j2 = 0; j2 < 2; ++j2) {
        float4 o = { s8x[i2][j2] * (1.f/64.f), s8y[i2][j2] * (1.f/64.f),
                     s8z[i2][j2] * (1.f/64.f), s8w[i2][j2] * (1.f/64.f) };
        *(float4*)(w8 + ((size_t)b * 64 + (P * 2 + i2) * 8 + (Q * 2 + j2)) * D_ + q * 4) = o;
      }
    float4 o4 = { s4x * (1.f/256.f), s4y * (1.f/256.f), s4z * (1.f/256.f), s4w * (1.f/256.f) };
    *(float4*)(w4 + ((size_t)b * 16 + P * 4 + Q) * D_ + q * 4) = o4;
  }
}

// ---------------- k-means++ seeding, JAX partitionable-threefry exact ----------------
// Grid: 96 blocks (si = blk/32; b = blk%32), 256 threads.
__global__ __launch_bounds__(256) void kmeans_kernel(const float* __restrict__ ws,
                                                     float* __restrict__ out) {
  int blk = blockIdx.x;
  int si = blk / 32;
  int b  = blk % 32;
  int n  = (si == 0) ? 16 : (si == 1) ? 64 : 256;

  const float* pooled;
  if (si == 0)      pooled = ws + (size_t)b * 16  * D_;
  else if (si == 1) pooled = ws + 196608 + (size_t)b * 64  * D_;
  else              pooled = ws + 983040 + (size_t)b * 256 * D_;
  float* ob = out + ((size_t)b * 12 + si * 4) * D_;

  __shared__ float minsq[256];
  __shared__ __align__(16) float csh[D_];
  __shared__ uint32_t skey[3][2];
  __shared__ int sidx;
  __shared__ float ssum;
  __shared__ float wred[4];
  __shared__ float wmaxv[4];
  __shared__ int   wmaxi[4];

  int tid  = threadIdx.x;
  int lane = tid & 63;
  int wv   = tid >> 6;

  if (tid == 0) {
    // base = key(42); folded = fold_in(base, si); bkey = split(folded,32)[b]
    uint32_t f0, f1, bk0, bk1;
    tf2x32(0u, 42u, 0u, (uint32_t)si, f0, f1);
    tf2x32(f0, f1, 0u, (uint32_t)b, bk0, bk1);
    // k0, k1 = split(bkey)
    uint32_t k00, k01, k10, k11;
    tf2x32(bk0, bk1, 0u, 0u, k00, k01);
    tf2x32(bk0, bk1, 0u, 1u, k10, k11);
    // randint(k0, (), 0, n): _, kk2 = split(k0); lower = random_bits(kk2); idx0 = lower % n
    uint32_t q0, q1, l0, l1;
    tf2x32(k00, k01, 0u, 1u, q0, q1);
    tf2x32(q0, q1, 0u, 0u, l0, l1);
    sidx = (int)((l0 ^ l1) & (uint32_t)(n - 1));
    // step keys = split(k1, 3)
    for (int t = 0; t < 3; ++t) {
      uint32_t a, bb;
      tf2x32(k10, k11, 0u, (uint32_t)t, a, bb);
      skey[t][0] = a; skey[t][1] = bb;
    }
  }
  minsq[tid] = 0.f;            // pad (tid >= n stays 0 -> exact +0 in sums)
  __syncthreads();

  // c0: gather into LDS + output slot 0
  for (int j = tid; j < D_; j += 256) {
    float v = pooled[(size_t)sidx * D_ + j];
    csh[j] = v;
    ob[j] = v;
  }
  __syncthreads();

  // min_sq = ||feats - c0||^2  (float4, same component add order as scalar version)
  if (tid < n) {
    const float4* row = (const float4*)(pooled + (size_t)tid * D_);
    const float4* cc  = (const float4*)csh;
    float acc = 0.f;
    #pragma unroll 8
    for (int j2 = 0; j2 < 96; ++j2) {
      float4 r = row[j2], c4 = cc[j2];
      float dx = r.x - c4.x, dy = r.y - c4.y, dz = r.z - c4.z, dw = r.w - c4.w;
      acc += dx * dx; acc += dy * dy; acc += dz * dz; acc += dw * dw;
    }
    minsq[tid] = acc;
  }
  __syncthreads();

  const float TINY = __uint_as_float(0x00800000u);  // f32 tiny

  for (int t = 0; t < 3; ++t) {
    // --- parallel sum(min_sq) ---
    float v = minsq[tid];
    #pragma unroll
    for (int m = 1; m < 64; m <<= 1) v += __shfl_xor(v, m);
    if (lane == 0) wred[wv] = v;
    __syncthreads();
    if (tid == 0) ssum = ((wred[0] + wred[1]) + (wred[2] + wred[3])) + 1e-8f;
    __syncthreads();

    // --- z_i = gumbel_i + log(prob_i + 1e-12) ---
    float z = -1e30f;
    if (tid < n) {
      float prob  = minsq[tid] / ssum;
      float logit = logf(prob + 1e-12f);
      uint32_t y0, y1;
      tf2x32(skey[t][0], skey[t][1], 0u, (uint32_t)tid, y0, y1);
      uint32_t bits = y0 ^ y1;
      float f = __uint_as_float((bits >> 9) | 0x3F800000u) - 1.0f;
      float u = (f > 0.f) ? f : TINY;
      float g = -logf(-logf(u));
      z = g + logit;
    }

    // --- parallel argmax, first-occurrence tie-break (smaller idx wins) ---
    float bv = z; int bi = tid;
    #pragma unroll
    for (int m = 1; m < 64; m <<= 1) {
      float ov = __shfl_xor(bv, m);
      int   oi = __shfl_xor(bi, m);
      if (ov > bv || (ov == bv && oi < bi)) { bv = ov; bi = oi; }
    }
    if (lane == 0) { wmaxv[wv] = bv; wmaxi[wv] = bi; }
    __syncthreads();
    if (tid == 0) {
      float cv = wmaxv[0]; int ci = wmaxi[0];
      for (int w2 = 1; w2 < 4; ++w2)
        if (wmaxv[w2] > cv || (wmaxv[w2] == cv && wmaxi[w2] < ci)) { cv = wmaxv[w2]; ci = wmaxi[w2]; }
      sidx = ci;
    }
    __syncthreads();

    // --- gather center, write out ---
    for (int j = tid; j < D_; j += 256) {
      float vv = pooled[(size_t)sidx * D_ + j];
      csh[j] = vv;
      ob[(size_t)(t + 1) * D_ + j] = vv;
    }
    __syncthreads();

    // --- min_sq = min(min_sq, dist^2) ---
    if (tid < n) {
      const float4* row = (const float4*)(pooled + (size_t)tid * D_);
      const float4* cc  = (const float4*)csh;
      float acc = 0.f;
      #pragma unroll 8
      for (int j2 = 0; j2 < 96; ++j2) {
        float4 r = row[j2], c4 = cc[j2];
        float dx = r.x - c4.x, dy = r.y - c4.y, dz = r.z - c4.z, dw = r.w - c4.w;
        acc += dx * dx; acc += dy * dy; acc += dz * dz; acc += dw * dw;
      }
      minsq[tid] = fminf(minsq[tid], acc);
    }
    __syncthreads();
  }
}

extern "C" void kernel_launch(void* const* d_in, const int* in_sizes, int n_in,
                              void* d_out, int out_size, void* d_ws, size_t ws_size,
                              hipStream_t stream) {
  const float* feats = (const float*)d_in[0];
  float* out = (float*)d_out;
  float* ws  = (float*)d_ws;   // uses 16,515,072 bytes (4,128,768 floats)

  pool_kernel<<<512, 384, 0, stream>>>(feats, ws);
  kmeans_kernel<<<96, 256, 0, stream>>>(ws, out);
}

// Round 3
// 66.429 us; speedup vs baseline: 1.7318x; 1.3240x over previous
//
#include <hip/hip_runtime.h>
#include <stdint.h>

#define D_ 384
#define NPTS 4096
#define W4_OFF 0
#define W8_OFF 196608
#define W16_OFF 983040

// ---------------- Threefry-2x32 (JAX-exact, 20 rounds) ----------------
__device__ __forceinline__ void tf_round(uint32_t& x0, uint32_t& x1, int r) {
  x0 += x1;
  x1 = (x1 << r) | (x1 >> (32 - r));
  x1 ^= x0;
}

__device__ void tf2x32(uint32_t k0, uint32_t k1, uint32_t x0, uint32_t x1,
                       uint32_t& y0, uint32_t& y1) {
  uint32_t ks2 = k0 ^ k1 ^ 0x1BD11BDAu;
  x0 += k0; x1 += k1;
  tf_round(x0, x1, 13); tf_round(x0, x1, 15); tf_round(x0, x1, 26); tf_round(x0, x1, 6);
  x0 += k1; x1 += ks2 + 1u;
  tf_round(x0, x1, 17); tf_round(x0, x1, 29); tf_round(x0, x1, 16); tf_round(x0, x1, 24);
  x0 += ks2; x1 += k0 + 2u;
  tf_round(x0, x1, 13); tf_round(x0, x1, 15); tf_round(x0, x1, 26); tf_round(x0, x1, 6);
  x0 += k0; x1 += k1 + 3u;
  tf_round(x0, x1, 17); tf_round(x0, x1, 29); tf_round(x0, x1, 16); tf_round(x0, x1, 24);
  x0 += k1; x1 += ks2 + 4u;
  tf_round(x0, x1, 13); tf_round(x0, x1, 15); tf_round(x0, x1, 26); tf_round(x0, x1, 6);
  x0 += ks2; x1 += k0 + 5u;
  y0 = x0; y1 = x1;
}

// ---------------- pool16: w16[b][cell][d] = mean of 4x4 block ----------------
// One thread per (b, cell, dim-quad): 32*256*96 = 786432 threads. 16 float4
// loads (each wave's lanes sweep q -> 1KB contiguous per instr), 1 store.
__global__ __launch_bounds__(256) void pool16_kernel(const float* __restrict__ feats,
                                                     float* __restrict__ ws) {
  int g = blockIdx.x * 256 + threadIdx.x;
  int q = g % 96;
  int cell = (g / 96) & 255;
  int b = g / (96 * 256);
  int ch = cell >> 4, cw = cell & 15;
  const float* fb = feats + (size_t)b * NPTS * D_;
  float ax = 0.f, ay = 0.f, az = 0.f, aw = 0.f;
  #pragma unroll
  for (int dh = 0; dh < 4; ++dh) {
    int h = ch * 4 + dh;
    #pragma unroll
    for (int dw = 0; dw < 4; ++dw) {
      int w = cw * 4 + dw;
      float4 v = *(const float4*)(fb + ((size_t)(h * 64 + w)) * D_ + q * 4);
      ax += v.x; ay += v.y; az += v.z; aw += v.w;
    }
  }
  float4 o = { ax * (1.f/16.f), ay * (1.f/16.f), az * (1.f/16.f), aw * (1.f/16.f) };
  *(float4*)(ws + W16_OFF + ((size_t)(b * 256 + cell)) * D_ + q * 4) = o;
}

// ---------------- pool8: w8 = mean of 4 w16 cells ----------------
__global__ __launch_bounds__(256) void pool8_kernel(float* __restrict__ ws) {
  int g = blockIdx.x * 256 + threadIdx.x;      // 32*64*96 = 196608
  int q = g % 96;
  int c8 = (g / 96) & 63;
  int b = g / (96 * 64);
  int p = c8 >> 3, r = c8 & 7;
  float ax = 0.f, ay = 0.f, az = 0.f, aw = 0.f;
  #pragma unroll
  for (int a = 0; a < 2; ++a)
    #pragma unroll
    for (int c = 0; c < 2; ++c) {
      int cell = (p * 2 + a) * 16 + (r * 2 + c);
      float4 v = *(const float4*)(ws + W16_OFF + ((size_t)(b * 256 + cell)) * D_ + q * 4);
      ax += v.x; ay += v.y; az += v.z; aw += v.w;
    }
  float4 o = { ax * 0.25f, ay * 0.25f, az * 0.25f, aw * 0.25f };
  *(float4*)(ws + W8_OFF + ((size_t)(b * 64 + c8)) * D_ + q * 4) = o;
}

// ---------------- pool4: w4 = mean of 4 w8 cells ----------------
__global__ __launch_bounds__(256) void pool4_kernel(float* __restrict__ ws) {
  int g = blockIdx.x * 256 + threadIdx.x;      // 32*16*96 = 49152
  int q = g % 96;
  int c4 = (g / 96) & 15;
  int b = g / (96 * 16);
  int p = c4 >> 2, r = c4 & 3;
  float ax = 0.f, ay = 0.f, az = 0.f, aw = 0.f;
  #pragma unroll
  for (int a = 0; a < 2; ++a)
    #pragma unroll
    for (int c = 0; c < 2; ++c) {
      int cell = (p * 2 + a) * 8 + (r * 2 + c);
      float4 v = *(const float4*)(ws + W8_OFF + ((size_t)(b * 64 + cell)) * D_ + q * 4);
      ax += v.x; ay += v.y; az += v.z; aw += v.w;
    }
  float4 o = { ax * 0.25f, ay * 0.25f, az * 0.25f, aw * 0.25f };
  *(float4*)(ws + W4_OFF + ((size_t)(b * 16 + c4)) * D_ + q * 4) = o;
}

// ---------------- k-means++ seeding, rows register-resident ----------------
// 96 blocks (si = blk/32, b = blk%32), 512 threads. 2 threads per row, each
// holding 48 float4 (192 floats) of its row in VGPRs. Centers broadcast via LDS.
__global__ __launch_bounds__(512) void kmeans_kernel(const float* __restrict__ ws,
                                                     float* __restrict__ out) {
  int blk = blockIdx.x;
  int si = blk / 32;
  int b  = blk % 32;
  int n  = (si == 0) ? 16 : (si == 1) ? 64 : 256;

  const float* pooled;
  if (si == 0)      pooled = ws + W4_OFF  + (size_t)b * 16  * D_;
  else if (si == 1) pooled = ws + W8_OFF  + (size_t)b * 64  * D_;
  else              pooled = ws + W16_OFF + (size_t)b * 256 * D_;
  float* ob = out + ((size_t)b * 12 + si * 4) * D_;

  __shared__ __align__(16) float4 csh4[96];   // one center row
  __shared__ float minsq[256];
  __shared__ uint32_t skey[3][2];
  __shared__ int sidx;
  __shared__ float ssum;
  __shared__ float wred[4];
  __shared__ float wmaxv[4];
  __shared__ int   wmaxi[4];

  int tid  = threadIdx.x;
  int row  = tid >> 1;        // 0..255
  int part = tid & 1;         // half-row owner
  int lane = tid & 63;
  int wv   = tid >> 6;

  if (tid == 0) {
    // base = key(42); folded = fold_in(base, si); bkey = split(folded,32)[b]
    uint32_t f0, f1, bk0, bk1;
    tf2x32(0u, 42u, 0u, (uint32_t)si, f0, f1);
    tf2x32(f0, f1, 0u, (uint32_t)b, bk0, bk1);
    uint32_t k00, k01, k10, k11;
    tf2x32(bk0, bk1, 0u, 0u, k00, k01);     // k0 = split(bkey)[0]
    tf2x32(bk0, bk1, 0u, 1u, k10, k11);     // k1 = split(bkey)[1]
    // randint(k0,(),0,n): _, kk2 = split(k0); lower = bits(kk2); idx = lower % n
    uint32_t q0, q1, l0, l1;
    tf2x32(k00, k01, 0u, 1u, q0, q1);
    tf2x32(q0, q1, 0u, 0u, l0, l1);
    sidx = (int)((l0 ^ l1) & (uint32_t)(n - 1));
    for (int t = 0; t < 3; ++t) {           // step keys = split(k1, 3)
      uint32_t a, bb;
      tf2x32(k10, k11, 0u, (uint32_t)t, a, bb);
      skey[t][0] = a; skey[t][1] = bb;
    }
  }
  if (tid < 256) minsq[tid] = 0.f;

  // load this thread's half-row into registers (contiguous 768B per thread)
  float4 xr[48];
  if (row < n) {
    const float4* rp = (const float4*)(pooled + (size_t)row * D_ + part * 192);
    #pragma unroll
    for (int k = 0; k < 48; ++k) xr[k] = rp[k];
  }
  __syncthreads();   // sidx + minsq ready

  // c0: owners write their registers to LDS + output slot 0
  if (row == sidx) {
    float4* cb = csh4 + part * 48;
    float4* op = (float4*)(ob + part * 192);
    #pragma unroll
    for (int k = 0; k < 48; ++k) { cb[k] = xr[k]; op[k] = xr[k]; }
  }
  __syncthreads();

  // min_sq = ||x - c0||^2
  if (row < n) {
    float acc = 0.f;
    #pragma unroll
    for (int k = 0; k < 48; ++k) {
      float4 c4 = csh4[part * 48 + k];
      float dx = xr[k].x - c4.x, dy = xr[k].y - c4.y;
      float dz = xr[k].z - c4.z, dw = xr[k].w - c4.w;
      acc += dx * dx; acc += dy * dy; acc += dz * dz; acc += dw * dw;
    }
    acc += __shfl_xor(acc, 1);              // combine the 2 half-rows
    if (part == 0) minsq[row] = acc;
  }
  __syncthreads();

  const float TINY = __uint_as_float(0x00800000u);  // f32 tiny

  for (int t = 0; t < 3; ++t) {
    // --- parallel sum(min_sq) over 256 slots (zeros pad) ---
    if (tid < 256) {
      float v = minsq[tid];
      #pragma unroll
      for (int m = 1; m < 64; m <<= 1) v += __shfl_xor(v, m);
      if (lane == 0) wred[wv] = v;
    }
    __syncthreads();
    if (tid == 0) ssum = ((wred[0] + wred[1]) + (wred[2] + wred[3])) + 1e-8f;
    __syncthreads();

    // --- z_i = gumbel_i + log(prob_i + 1e-12); argmax (first occurrence) ---
    if (tid < 256) {
      float z = -1e30f;
      if (tid < n) {
        float prob  = minsq[tid] / ssum;
        float logit = logf(prob + 1e-12f);
        uint32_t y0, y1;
        tf2x32(skey[t][0], skey[t][1], 0u, (uint32_t)tid, y0, y1);
        uint32_t bits = y0 ^ y1;
        float f = __uint_as_float((bits >> 9) | 0x3F800000u) - 1.0f;
        float u = (f > 0.f) ? f : TINY;
        z = -logf(-logf(u)) + logit;
      }
      float bv = z; int bi = tid;
      #pragma unroll
      for (int m = 1; m < 64; m <<= 1) {
        float ov = __shfl_xor(bv, m);
        int   oi = __shfl_xor(bi, m);
        if (ov > bv || (ov == bv && oi < bi)) { bv = ov; bi = oi; }
      }
      if (lane == 0) { wmaxv[wv] = bv; wmaxi[wv] = bi; }
    }
    __syncthreads();
    if (tid == 0) {
      float cv = wmaxv[0]; int ci = wmaxi[0];
      for (int w2 = 1; w2 < 4; ++w2)
        if (wmaxv[w2] > cv || (wmaxv[w2] == cv && wmaxi[w2] < ci)) { cv = wmaxv[w2]; ci = wmaxi[w2]; }
      sidx = ci;
    }
    __syncthreads();

    // --- new center from owners' registers -> LDS + out ---
    if (row == sidx) {
      float4* cb = csh4 + part * 48;
      float4* op = (float4*)(ob + (size_t)(t + 1) * D_ + part * 192);
      #pragma unroll
      for (int k = 0; k < 48; ++k) { cb[k] = xr[k]; op[k] = xr[k]; }
    }
    __syncthreads();

    // --- min_sq = min(min_sq, ||x - c||^2) ---
    if (row < n) {
      float acc = 0.f;
      #pragma unroll
      for (int k = 0; k < 48; ++k) {
        float4 c4 = csh4[part * 48 + k];
        float dx = xr[k].x - c4.x, dy = xr[k].y - c4.y;
        float dz = xr[k].z - c4.z, dw = xr[k].w - c4.w;
        acc += dx * dx; acc += dy * dy; acc += dz * dz; acc += dw * dw;
      }
      acc += __shfl_xor(acc, 1);
      if (part == 0) minsq[row] = fminf(minsq[row], acc);
    }
    __syncthreads();
  }
}

extern "C" void kernel_launch(void* const* d_in, const int* in_sizes, int n_in,
                              void* d_out, int out_size, void* d_ws, size_t ws_size,
                              hipStream_t stream) {
  const float* feats = (const float*)d_in[0];
  float* out = (float*)d_out;
  float* ws  = (float*)d_ws;   // uses 16,515,072 bytes

  pool16_kernel<<<3072, 256, 0, stream>>>(feats, ws);
  pool8_kernel<<<768, 256, 0, stream>>>(ws);
  pool4_kernel<<<192, 256, 0, stream>>>(ws);
  kmeans_kernel<<<96, 512, 0, stream>>>(ws, out);
}